// Round 1
// baseline (1284.865 us; speedup 1.0000x reference)
//
#include <hip/hip_runtime.h>
#include <math.h>

// Problem constants: B=4, L=T=2048, H=8, E=64, C=H*E=512, top_k=7
#define TI 128
#define TJ 128
#define KC 16

// ---------------------------------------------------------------------------
// Temporal LSE: for each batch b, row i in [0,4096): LSE over j != i of
// dot(z_b[i], z_b[j]) where z_b[j] = Q[b,j,:] (j<2048) else K[b,j-2048,:].
// Each block: (b, row-block of 128, j-half of 2048). Online softmax over
// j-tiles of 128. Writes partial (m, s) per row; merged later.
// ---------------------------------------------------------------------------
__global__ __launch_bounds__(256) void temporal_lse_kernel(
    const float* __restrict__ Q, const float* __restrict__ K,
    float* __restrict__ part /* [4][2][4096][2] */) {
  int bid = blockIdx.x;          // 0..255
  int b = bid >> 6;
  int sub = bid & 63;
  int row0 = (sub >> 1) * TI;    // 32 row-blocks
  int half = sub & 1;
  int jstart = half * 2048;

  const float* Zq = Q + b * 2048 * 512;
  const float* Zk = K + b * 2048 * 512;

  __shared__ float As[KC][TI];   // 8 KB, stored [k][row]
  __shared__ float Bs[KC][TJ];   // 8 KB, stored [k][col]

  int tid = threadIdx.x;
  int tx = tid & 15, ty = tid >> 4;

  float m[8], s[8];
#pragma unroll
  for (int r = 0; r < 8; r++) { m[r] = -INFINITY; s[r] = 0.f; }

  for (int jt = 0; jt < 2048 / TJ; ++jt) {
    int j0 = jstart + jt * TJ;
    float acc[8][8];
#pragma unroll
    for (int r = 0; r < 8; r++)
#pragma unroll
      for (int c = 0; c < 8; c++) acc[r][c] = 0.f;

    for (int kc = 0; kc < 512 / KC; ++kc) {
      int k0 = kc * KC;
      // Stage A-chunk [16][128] and B-chunk [16][128]: 2048 floats each.
#pragma unroll
      for (int it = 0; it < 2; ++it) {
        int idx = tid + it * 256;      // 0..511
        int rr = idx >> 2;             // 0..127
        int kq = idx & 3;              // float4 index along k
        int grow = row0 + rr;
        const float* srcA =
            (grow < 2048 ? Zq + grow * 512 : Zk + (grow - 2048) * 512) + k0 + kq * 4;
        float4 va = *(const float4*)srcA;
        As[kq * 4 + 0][rr] = va.x;
        As[kq * 4 + 1][rr] = va.y;
        As[kq * 4 + 2][rr] = va.z;
        As[kq * 4 + 3][rr] = va.w;
        int gcol = j0 + rr;
        const float* srcB =
            (gcol < 2048 ? Zq + gcol * 512 : Zk + (gcol - 2048) * 512) + k0 + kq * 4;
        float4 vb = *(const float4*)srcB;
        Bs[kq * 4 + 0][rr] = vb.x;
        Bs[kq * 4 + 1][rr] = vb.y;
        Bs[kq * 4 + 2][rr] = vb.z;
        Bs[kq * 4 + 3][rr] = vb.w;
      }
      __syncthreads();
#pragma unroll
      for (int kk = 0; kk < KC; ++kk) {
        const float4* Ap = (const float4*)(&As[kk][ty * 8]);
        const float4* Bp = (const float4*)(&Bs[kk][tx * 8]);
        float4 a0 = Ap[0], a1 = Ap[1];
        float4 b0 = Bp[0], b1 = Bp[1];
        float av[8] = {a0.x, a0.y, a0.z, a0.w, a1.x, a1.y, a1.z, a1.w};
        float bv[8] = {b0.x, b0.y, b0.z, b0.w, b1.x, b1.y, b1.z, b1.w};
#pragma unroll
        for (int r = 0; r < 8; r++)
#pragma unroll
          for (int c = 0; c < 8; c++) acc[r][c] = fmaf(av[r], bv[c], acc[r][c]);
      }
      __syncthreads();
    }

    // Epilogue: per-row tile max + sumexp (butterfly over the 16 tx lanes),
    // then online merge into running (m, s). Diagonal j==i excluded.
    int Rbase = row0 + ty * 8;
    int Cbase = j0 + tx * 8;
#pragma unroll
    for (int r = 0; r < 8; r++) {
      int R = Rbase + r;
#pragma unroll
      for (int c = 0; c < 8; c++)
        if (R == Cbase + c) acc[r][c] = -INFINITY;
      float mt = acc[r][0];
#pragma unroll
      for (int c = 1; c < 8; c++) mt = fmaxf(mt, acc[r][c]);
      mt = fmaxf(mt, __shfl_xor(mt, 1, 64));
      mt = fmaxf(mt, __shfl_xor(mt, 2, 64));
      mt = fmaxf(mt, __shfl_xor(mt, 4, 64));
      mt = fmaxf(mt, __shfl_xor(mt, 8, 64));
      float st = 0.f;
#pragma unroll
      for (int c = 0; c < 8; c++) st += __expf(acc[r][c] - mt);  // exp(-inf)=0
      st += __shfl_xor(st, 1, 64);
      st += __shfl_xor(st, 2, 64);
      st += __shfl_xor(st, 4, 64);
      st += __shfl_xor(st, 8, 64);
      float nm = fmaxf(m[r], mt);
      s[r] = s[r] * __expf(m[r] - nm) + st * __expf(mt - nm);
      m[r] = nm;
    }
  }

  if (tx == 0) {
#pragma unroll
    for (int r = 0; r < 8; r++) {
      int R = row0 + ty * 8 + r;
      int o = ((b * 2 + half) * 4096 + R) * 2;
      part[o] = m[r];
      part[o + 1] = s[r];
    }
  }
}

// Merge the two j-half partials into final temporal LSE per (b, row).
__global__ void merge_lse_kernel(const float* __restrict__ part,
                                 float* __restrict__ lse_temp /* [4][4096] */) {
  int i = blockIdx.x * blockDim.x + threadIdx.x;  // 0..16383
  if (i >= 4 * 4096) return;
  int b = i >> 12, row = i & 4095;
  int o0 = ((b * 2 + 0) * 4096 + row) * 2;
  int o1 = ((b * 2 + 1) * 4096 + row) * 2;
  float m0 = part[o0], s0 = part[o0 + 1];
  float m1 = part[o1], s1 = part[o1 + 1];
  float M = fmaxf(m0, m1);
  float ssum = s0 * __expf(m0 - M) + s1 * __expf(m1 - M);
  lse_temp[i] = M + __logf(ssum);
}

// ---------------------------------------------------------------------------
// Instance LSE: per t, 8x8 gram of {Q[0..3,t], K[0..3,t]}; LSE over j != i
// per row. One wave per t; lane (i,j) = (lane>>3, lane&7) owns one dot.
// Also writes posdot[b][t] = dot(Q[b,t], K[b,t]).
// ---------------------------------------------------------------------------
__global__ __launch_bounds__(256) void instance_kernel(
    const float* __restrict__ Q, const float* __restrict__ K,
    float* __restrict__ lse_inst /* [2048][8] */,
    float* __restrict__ posdot /* [4][2048] */) {
  int t = (blockIdx.x * 256 + threadIdx.x) >> 6;
  if (t >= 2048) return;
  int lane = threadIdx.x & 63;
  int i = lane >> 3, j = lane & 7;
  const float* vi = (i < 4) ? Q + (i * 2048 + t) * 512 : K + ((i - 4) * 2048 + t) * 512;
  const float* vj = (j < 4) ? Q + (j * 2048 + t) * 512 : K + ((j - 4) * 2048 + t) * 512;
  float d = 0.f;
  for (int c = 0; c < 512; c += 4) {
    float4 a = *(const float4*)(vi + c);
    float4 bb = *(const float4*)(vj + c);
    d = fmaf(a.x, bb.x, d);
    d = fmaf(a.y, bb.y, d);
    d = fmaf(a.z, bb.z, d);
    d = fmaf(a.w, bb.w, d);
  }
  float dd = (i == j) ? -INFINITY : d;
  float mt = dd;
  mt = fmaxf(mt, __shfl_xor(mt, 1, 64));
  mt = fmaxf(mt, __shfl_xor(mt, 2, 64));
  mt = fmaxf(mt, __shfl_xor(mt, 4, 64));
  float e = __expf(dd - mt);
  e += __shfl_xor(e, 1, 64);
  e += __shfl_xor(e, 2, 64);
  e += __shfl_xor(e, 4, 64);
  if (j == 0) lse_inst[t * 8 + i] = mt + __logf(e);
  if (i < 4 && j == i + 4) posdot[i * 2048 + t] = d;
}

// corrmean[t] = mean_b corr[b][t]
__global__ void combine_kernel(const float* __restrict__ lse_inst,
                               const float* __restrict__ lse_temp,
                               const float* __restrict__ posdot,
                               float* __restrict__ corrmean) {
  int t = blockIdx.x * blockDim.x + threadIdx.x;
  if (t >= 2048) return;
  float sum = 0.f;
#pragma unroll
  for (int b = 0; b < 4; b++) {
    float c = 0.25f * (lse_inst[t * 8 + b] + lse_inst[t * 8 + 4 + b] +
                       lse_temp[b * 4096 + t] + lse_temp[b * 4096 + 2048 + t]) -
              posdot[b * 2048 + t];
    sum += c;
  }
  corrmean[t] = sum * 0.25f;
}

// Top-7 of corrmean (only the index SET matters for the output).
__global__ __launch_bounds__(256) void topk_kernel(const float* __restrict__ corrmean,
                                                   int* __restrict__ index_out) {
  __shared__ float vals[2048];
  __shared__ float cand_v[256];
  __shared__ int cand_i[256];
  int tid = threadIdx.x;
  for (int i = tid; i < 2048; i += 256) vals[i] = corrmean[i];
  __syncthreads();
  for (int k = 0; k < 7; k++) {
    float bv = -INFINITY;
    int bi = -1;
    for (int i = tid; i < 2048; i += 256) {
      float v = vals[i];
      if (v > bv) { bv = v; bi = i; }
    }
    cand_v[tid] = bv;
    cand_i[tid] = bi;
    __syncthreads();
    if (tid == 0) {
      float BV = -INFINITY;
      int BI = -1;
      for (int t2 = 0; t2 < 256; t2++) {
        if (cand_v[t2] > BV || (cand_v[t2] == BV && cand_i[t2] < BI && cand_i[t2] >= 0)) {
          BV = cand_v[t2];
          BI = cand_i[t2];
        }
      }
      index_out[k] = BI;
      vals[BI] = -INFINITY;
    }
    __syncthreads();
  }
}

// Cumsum over L per (b,h,e), chunked. Phase 1: per-chunk sums.
__global__ __launch_bounds__(64) void cumsum_phase1(const float* __restrict__ V,
                                                    float* __restrict__ partial) {
  int blk = blockIdx.x;        // (b*8+h)*16 + chunk
  int chunk = blk & 15;
  int bh = blk >> 4;
  int h = bh & 7, b = bh >> 3;
  int e = threadIdx.x;
  float s = 0.f;
  int l0 = chunk * 128;
  for (int l = l0; l < l0 + 128; l++)
    s += V[((b * 2048 + l) * 8 + h) * 64 + e];
  partial[blk * 64 + e] = s;
}

// Phase 2: offset = sum of preceding chunk partials; local scan + write,
// replacing the 7 selected positions with running-mean = cumsum/(l+1).
__global__ __launch_bounds__(64) void cumsum_phase2(const float* __restrict__ V,
                                                    const float* __restrict__ partial,
                                                    const int* __restrict__ index,
                                                    float* __restrict__ out) {
  int blk = blockIdx.x;
  int chunk = blk & 15;
  int bh = blk >> 4;
  int h = bh & 7, b = bh >> 3;
  int e = threadIdx.x;
  float run = 0.f;
  for (int c = 0; c < chunk; c++) run += partial[(bh * 16 + c) * 64 + e];
  int idx[7];
#pragma unroll
  for (int k = 0; k < 7; k++) idx[k] = index[k];
  int l0 = chunk * 128;
  for (int l = l0; l < l0 + 128; l++) {
    run += V[((b * 2048 + l) * 8 + h) * 64 + e];
    float o = run;
    bool special = false;
#pragma unroll
    for (int k = 0; k < 7; k++) special = special || (idx[k] == l);
    if (special) o = run / (float)(l + 1);
    out[(bh * 2048 + l) * 64 + e] = o;
  }
}

extern "C" void kernel_launch(void* const* d_in, const int* in_sizes, int n_in,
                              void* d_out, int out_size, void* d_ws, size_t ws_size,
                              hipStream_t stream) {
  const float* Q = (const float*)d_in[0];  // (4,2048,8,64) = (4,2048,512)
  const float* K = (const float*)d_in[1];
  const float* V = (const float*)d_in[2];
  float* out = (float*)d_out;              // (4,8,2048,64)
  float* ws = (float*)d_ws;

  // Workspace layout (floats):
  float* part = ws;                 // 4*2*4096*2   = 65536
  float* lse_t = ws + 65536;        // 4*4096       = 16384
  float* lse_i = ws + 81920;        // 2048*8       = 16384
  float* posd = ws + 98304;         // 4*2048       = 8192
  float* cmean = ws + 106496;       // 2048
  int* idx = (int*)(ws + 108544);   // 7 (+1 pad)
  float* partial = ws + 108552;     // 4*8*16*64    = 32768
  // total ~141320 floats ~ 565 KB

  temporal_lse_kernel<<<256, 256, 0, stream>>>(Q, K, part);
  instance_kernel<<<512, 256, 0, stream>>>(Q, K, lse_i, posd);
  merge_lse_kernel<<<64, 256, 0, stream>>>(part, lse_t);
  combine_kernel<<<8, 256, 0, stream>>>(lse_i, lse_t, posd, cmean);
  topk_kernel<<<1, 256, 0, stream>>>(cmean, idx);
  cumsum_phase1<<<512, 64, 0, stream>>>(V, partial);
  cumsum_phase2<<<512, 64, 0, stream>>>(V, partial, idx, out);
}

// Round 2
// 409.090 us; speedup vs baseline: 3.1408x; 3.1408x over previous
//
#include <hip/hip_runtime.h>
#include <math.h>

// Problem constants: B=4, L=T=2048, H=8, E=64, C=H*E=512, top_k=7
// Output = cumsum(V) with top-7 rows (by corrmean) replaced by running mean.
// corr[b,t] = 0.25*(LSE_inst[t,b]+LSE_inst[t,4+b]+LSE_temp[b,t]+LSE_temp[b,2048+t])
//             - dot(Q[b,t],K[b,t])
// Temporal gram (4 x 4096x4096 over C=512) -> bf16 MFMA; only the top-7 index
// SET affects the output, so bf16 rounding (dot err ~0.13 << order-stat gap
// ~0.45) is safe. posdot + instance gram stay fp32.

typedef __attribute__((ext_vector_type(8))) short short8;
typedef __attribute__((ext_vector_type(8))) unsigned short ushort8;
typedef __attribute__((ext_vector_type(4))) float f32x4;

typedef const __attribute__((address_space(1))) void* gas_ptr;
typedef __attribute__((address_space(3))) void* las_ptr;

__device__ __forceinline__ void async_cp16(const void* g, void* l) {
  // LDS dest is wave-uniform base; HW adds lane*16 (m104/m108).
  __builtin_amdgcn_global_load_lds((gas_ptr)g, (las_ptr)l, 16, 0, 0);
}

__device__ __forceinline__ unsigned short f2bf(float x) {
  union { float f; unsigned int u; } v; v.f = x;
  unsigned int r = v.u + 0x7FFFu + ((v.u >> 16) & 1u);  // RNE
  return (unsigned short)(r >> 16);
}

// ---------------------------------------------------------------------------
// Convert Q,K fp32 -> Z bf16 [4][4096][512] (rows 0..2047 = Q, 2048.. = K)
// ---------------------------------------------------------------------------
__global__ __launch_bounds__(256) void convert_bf16_kernel(
    const float* __restrict__ Q, const float* __restrict__ K,
    unsigned short* __restrict__ Z) {
  int tid = blockIdx.x * 256 + threadIdx.x;  // 0..1048575
  int row = tid >> 6;                        // b*4096 + i
  int c0 = (tid & 63) * 8;
  int b = row >> 12, i = row & 4095;
  const float* src = (i < 2048)
      ? Q + ((size_t)(b * 2048 + i) * 512 + c0)
      : K + ((size_t)(b * 2048 + (i - 2048)) * 512 + c0);
  float4 v0 = ((const float4*)src)[0];
  float4 v1 = ((const float4*)src)[1];
  ushort8 o;
  o[0] = f2bf(v0.x); o[1] = f2bf(v0.y); o[2] = f2bf(v0.z); o[3] = f2bf(v0.w);
  o[4] = f2bf(v1.x); o[5] = f2bf(v1.y); o[6] = f2bf(v1.z); o[7] = f2bf(v1.w);
  *(ushort8*)(Z + (size_t)row * 512 + c0) = o;
}

// ---------------------------------------------------------------------------
// Temporal gram tile (128x128) via 16x16x32 bf16 MFMA + fused LSE partials.
// Grid (cj=32, ri=32, b=4). Per-tile per-row (max, sumexp) -> part[b][row][64].
// LDS layout [row][chunk] with chunk XOR-swizzled by (row>>1)&3 -> 2-way
// bank aliasing only (free). Staged via global_load_lds width=16.
// ---------------------------------------------------------------------------
__global__ __launch_bounds__(256) void temporal_gemm_kernel(
    const unsigned short* __restrict__ Z, float2* __restrict__ part) {
  int cj = blockIdx.x, ri = blockIdx.y, b = blockIdx.z;
  const unsigned short* Zb = Z + (size_t)b * 4096 * 512;

  __shared__ __align__(16) unsigned short As[128 * 32];
  __shared__ __align__(16) unsigned short Bs[128 * 32];

  int tid = threadIdx.x;
  int w = tid >> 6, lane = tid & 63;
  int wr = w >> 1, wc = w & 1;
  int lm = lane & 15, q = lane >> 4;
  int swz = q ^ ((lm >> 1) & 3);  // frag-read chunk swizzle

  // Staging: slot (row_loc = it*64 + w*16 + lane>>2, chunk_st = lane&3)
  // holds real k-chunk kq = chunk_st ^ ((row_loc>>1)&3) = chunk_st ^ ((lane>>3)&3)
  int srow = lane >> 2;
  int kq = (lane & 3) ^ ((lane >> 3) & 3);
  int rl0 = w * 16 + srow;
  int rl1 = 64 + rl0;
  const unsigned short* gA0 = Zb + (size_t)(ri * 128 + rl0) * 512 + kq * 8;
  const unsigned short* gA1 = Zb + (size_t)(ri * 128 + rl1) * 512 + kq * 8;
  const unsigned short* gB0 = Zb + (size_t)(cj * 128 + rl0) * 512 + kq * 8;
  const unsigned short* gB1 = Zb + (size_t)(cj * 128 + rl1) * 512 + kq * 8;
  unsigned short* lA0 = As + (w * 16) * 32;         // wave-uniform bases
  unsigned short* lA1 = As + (64 + w * 16) * 32;
  unsigned short* lB0 = Bs + (w * 16) * 32;
  unsigned short* lB1 = Bs + (64 + w * 16) * 32;

  f32x4 acc[4][4];
#pragma unroll
  for (int mi = 0; mi < 4; mi++)
#pragma unroll
    for (int ni = 0; ni < 4; ni++) acc[mi][ni] = (f32x4)(0.f);

  for (int kc = 0; kc < 16; ++kc) {
    int go = kc * 32;  // ushort offset along k
    async_cp16(gA0 + go, lA0);
    async_cp16(gA1 + go, lA1);
    async_cp16(gB0 + go, lB0);
    async_cp16(gB1 + go, lB1);
    __syncthreads();

    short8 af[4], bfr[4];
#pragma unroll
    for (int mi = 0; mi < 4; mi++) {
      int ar = wr * 64 + mi * 16 + lm;
      af[mi] = *(const short8*)(As + ar * 32 + swz * 8);
    }
#pragma unroll
    for (int ni = 0; ni < 4; ni++) {
      int bc = wc * 64 + ni * 16 + lm;
      bfr[ni] = *(const short8*)(Bs + bc * 32 + swz * 8);
    }
#pragma unroll
    for (int mi = 0; mi < 4; mi++)
#pragma unroll
      for (int ni = 0; ni < 4; ni++)
        acc[mi][ni] = __builtin_amdgcn_mfma_f32_16x16x32_bf16(
            af[mi], bfr[ni], acc[mi][ni], 0, 0, 0);
    __syncthreads();
  }

  // Epilogue: C/D layout col=lane&15, row=(lane>>4)*4+reg (m89-verified).
  // Per-row reduce across the 16 col-lanes (xor 1,2,4,8 keeps q fixed).
#pragma unroll
  for (int mi = 0; mi < 4; mi++) {
#pragma unroll
    for (int r = 0; r < 4; r++) {
      int R = ri * 128 + wr * 64 + mi * 16 + q * 4 + r;
      float vals[4];
      float mt = -INFINITY;
#pragma unroll
      for (int ni = 0; ni < 4; ni++) {
        float v = acc[mi][ni][r];
        int Cg = cj * 128 + wc * 64 + ni * 16 + lm;
        if (R == Cg) v = -INFINITY;  // exclude diagonal j==i
        vals[ni] = v;
        mt = fmaxf(mt, v);
      }
      mt = fmaxf(mt, __shfl_xor(mt, 1));
      mt = fmaxf(mt, __shfl_xor(mt, 2));
      mt = fmaxf(mt, __shfl_xor(mt, 4));
      mt = fmaxf(mt, __shfl_xor(mt, 8));
      float st = 0.f;
#pragma unroll
      for (int ni = 0; ni < 4; ni++) st += __expf(vals[ni] - mt);
      st += __shfl_xor(st, 1);
      st += __shfl_xor(st, 2);
      st += __shfl_xor(st, 4);
      st += __shfl_xor(st, 8);
      if (lm == 0) {
        float2 ms; ms.x = mt; ms.y = st;
        part[((size_t)(b * 4096 + R)) * 64 + cj * 2 + wc] = ms;
      }
    }
  }
}

// Merge 64 per-tile partials per row -> lse_temp[b*4096+row]. 1 wave/row.
__global__ __launch_bounds__(64) void merge_row_kernel(
    const float2* __restrict__ part, float* __restrict__ lse_temp) {
  int row = blockIdx.x;  // 0..16383
  int p = threadIdx.x;
  float2 v = part[(size_t)row * 64 + p];
  float M = v.x;
  M = fmaxf(M, __shfl_xor(M, 1));
  M = fmaxf(M, __shfl_xor(M, 2));
  M = fmaxf(M, __shfl_xor(M, 4));
  M = fmaxf(M, __shfl_xor(M, 8));
  M = fmaxf(M, __shfl_xor(M, 16));
  M = fmaxf(M, __shfl_xor(M, 32));
  float st = v.y * __expf(v.x - M);
  st += __shfl_xor(st, 1);
  st += __shfl_xor(st, 2);
  st += __shfl_xor(st, 4);
  st += __shfl_xor(st, 8);
  st += __shfl_xor(st, 16);
  st += __shfl_xor(st, 32);
  if (p == 0) lse_temp[row] = M + __logf(st);
}

// ---------------------------------------------------------------------------
// Instance LSE (fp32): per t, 8x8 gram of {Q[b,t],K[b,t]}; LSE_j!=i per row.
// Also posdot[b][t] = dot(Q[b,t],K[b,t]) in fp32.
// ---------------------------------------------------------------------------
__global__ __launch_bounds__(256) void instance_kernel(
    const float* __restrict__ Q, const float* __restrict__ K,
    float* __restrict__ lse_inst /* [2048][8] */,
    float* __restrict__ posdot /* [4][2048] */) {
  int t = (blockIdx.x * 256 + threadIdx.x) >> 6;
  if (t >= 2048) return;
  int lane = threadIdx.x & 63;
  int i = lane >> 3, j = lane & 7;
  const float* vi = (i < 4) ? Q + ((size_t)i * 2048 + t) * 512 : K + ((size_t)(i - 4) * 2048 + t) * 512;
  const float* vj = (j < 4) ? Q + ((size_t)j * 2048 + t) * 512 : K + ((size_t)(j - 4) * 2048 + t) * 512;
  float d = 0.f;
  for (int c = 0; c < 512; c += 4) {
    float4 a = *(const float4*)(vi + c);
    float4 bb = *(const float4*)(vj + c);
    d = fmaf(a.x, bb.x, d);
    d = fmaf(a.y, bb.y, d);
    d = fmaf(a.z, bb.z, d);
    d = fmaf(a.w, bb.w, d);
  }
  float dd = (i == j) ? -INFINITY : d;
  float mt = dd;
  mt = fmaxf(mt, __shfl_xor(mt, 1, 64));
  mt = fmaxf(mt, __shfl_xor(mt, 2, 64));
  mt = fmaxf(mt, __shfl_xor(mt, 4, 64));
  float e = __expf(dd - mt);
  e += __shfl_xor(e, 1, 64);
  e += __shfl_xor(e, 2, 64);
  e += __shfl_xor(e, 4, 64);
  if (j == 0) lse_inst[t * 8 + i] = mt + __logf(e);
  if (i < 4 && j == i + 4) posdot[i * 2048 + t] = d;
}

// corrmean[t] = mean_b corr[b][t]
__global__ void combine_kernel(const float* __restrict__ lse_inst,
                               const float* __restrict__ lse_temp,
                               const float* __restrict__ posdot,
                               float* __restrict__ corrmean) {
  int t = blockIdx.x * blockDim.x + threadIdx.x;
  if (t >= 2048) return;
  float sum = 0.f;
#pragma unroll
  for (int b = 0; b < 4; b++) {
    float c = 0.25f * (lse_inst[t * 8 + b] + lse_inst[t * 8 + 4 + b] +
                       lse_temp[b * 4096 + t] + lse_temp[b * 4096 + 2048 + t]) -
              posdot[b * 2048 + t];
    sum += c;
  }
  corrmean[t] = sum * 0.25f;
}

// Top-7 of corrmean (only the index SET matters for the output).
__global__ __launch_bounds__(256) void topk_kernel(const float* __restrict__ corrmean,
                                                   int* __restrict__ index_out) {
  __shared__ float vals[2048];
  __shared__ float cand_v[256];
  __shared__ int cand_i[256];
  int tid = threadIdx.x;
  for (int i = tid; i < 2048; i += 256) vals[i] = corrmean[i];
  __syncthreads();
  for (int k = 0; k < 7; k++) {
    float bv = -INFINITY;
    int bi = -1;
    for (int i = tid; i < 2048; i += 256) {
      float v = vals[i];
      if (v > bv) { bv = v; bi = i; }
    }
    cand_v[tid] = bv;
    cand_i[tid] = bi;
    __syncthreads();
    if (tid == 0) {
      float BV = -INFINITY;
      int BI = -1;
      for (int t2 = 0; t2 < 256; t2++) {
        if (cand_v[t2] > BV || (cand_v[t2] == BV && cand_i[t2] < BI && cand_i[t2] >= 0)) {
          BV = cand_v[t2];
          BI = cand_i[t2];
        }
      }
      index_out[k] = BI;
      vals[BI] = -INFINITY;
    }
    __syncthreads();
  }
}

// Cumsum over L per (b,h,e), chunked. Phase 1: per-chunk sums.
__global__ __launch_bounds__(64) void cumsum_phase1(const float* __restrict__ V,
                                                    float* __restrict__ partial) {
  int blk = blockIdx.x;  // (b*8+h)*16 + chunk
  int chunk = blk & 15;
  int bh = blk >> 4;
  int h = bh & 7, b = bh >> 3;
  int e = threadIdx.x;
  float s = 0.f;
  int l0 = chunk * 128;
  for (int l = l0; l < l0 + 128; l++)
    s += V[((size_t)(b * 2048 + l) * 8 + h) * 64 + e];
  partial[blk * 64 + e] = s;
}

// Phase 2: local scan + write; selected positions -> running mean.
__global__ __launch_bounds__(64) void cumsum_phase2(const float* __restrict__ V,
                                                    const float* __restrict__ partial,
                                                    const int* __restrict__ index,
                                                    float* __restrict__ out) {
  int blk = blockIdx.x;
  int chunk = blk & 15;
  int bh = blk >> 4;
  int h = bh & 7, b = bh >> 3;
  int e = threadIdx.x;
  float run = 0.f;
  for (int c = 0; c < chunk; c++) run += partial[(bh * 16 + c) * 64 + e];
  int idx[7];
#pragma unroll
  for (int k = 0; k < 7; k++) idx[k] = index[k];
  int l0 = chunk * 128;
  for (int l = l0; l < l0 + 128; l++) {
    run += V[((size_t)(b * 2048 + l) * 8 + h) * 64 + e];
    float o = run;
    bool special = false;
#pragma unroll
    for (int k = 0; k < 7; k++) special = special || (idx[k] == l);
    if (special) o = run / (float)(l + 1);
    out[((size_t)bh * 2048 + l) * 64 + e] = o;
  }
}

extern "C" void kernel_launch(void* const* d_in, const int* in_sizes, int n_in,
                              void* d_out, int out_size, void* d_ws, size_t ws_size,
                              hipStream_t stream) {
  const float* Q = (const float*)d_in[0];  // (4,2048,512)
  const float* K = (const float*)d_in[1];
  const float* V = (const float*)d_in[2];
  float* out = (float*)d_out;              // (4,8,2048,64)

  // Workspace layout:
  unsigned short* Z = (unsigned short*)d_ws;        // 4*4096*512 bf16 = 16.8 MB
  float* base = (float*)d_ws + 4 * 4096 * 512 / 2;  // after Z
  float2* part2 = (float2*)base;                    // 4*4096*64 float2 = 8.4 MB
  float* lse_t = base + 2 * 4 * 4096 * 64;          // 16384
  float* lse_i = lse_t + 16384;                     // 16384
  float* posd = lse_i + 16384;                      // 8192
  float* cmean = posd + 8192;                       // 2048
  int* idx = (int*)(cmean + 2048);                  // 8
  float* cpart = cmean + 2048 + 8;                  // 32768

  convert_bf16_kernel<<<4096, 256, 0, stream>>>(Q, K, Z);
  temporal_gemm_kernel<<<dim3(32, 32, 4), 256, 0, stream>>>(Z, part2);
  instance_kernel<<<512, 256, 0, stream>>>(Q, K, lse_i, posd);
  merge_row_kernel<<<16384, 64, 0, stream>>>(part2, lse_t);
  combine_kernel<<<8, 256, 0, stream>>>(lse_i, lse_t, posd, cmean);
  topk_kernel<<<1, 256, 0, stream>>>(cmean, idx);
  cumsum_phase1<<<512, 64, 0, stream>>>(V, cpart);
  cumsum_phase2<<<512, 64, 0, stream>>>(V, cpart, idx, out);
}

// Round 3
// 289.710 us; speedup vs baseline: 4.4350x; 1.4121x over previous
//
#include <hip/hip_runtime.h>
#include <math.h>

// Problem constants: B=4, L=T=2048, H=8, E=64, C=H*E=512, top_k=7
// Output = cumsum(V) with top-7 rows (by corrmean) replaced by running mean.
// corr[b,t] = 0.25*(LSE_inst[t,b]+LSE_inst[t,4+b]+LSE_temp[b,t]+LSE_temp[b,2048+t])
//             - dot(Q[b,t],K[b,t])
// Temporal gram (4 x 4096x4096 over C=512) -> bf16 MFMA; only the top-7 index
// SET affects the output, so bf16 rounding (dot err ~0.13 << order-stat gap
// ~0.45) is safe. posdot + instance gram stay fp32.

typedef __attribute__((ext_vector_type(8))) short short8;
typedef __attribute__((ext_vector_type(8))) unsigned short ushort8;
typedef __attribute__((ext_vector_type(4))) float f32x4;

typedef const __attribute__((address_space(1))) void* gas_ptr;
typedef __attribute__((address_space(3))) void* las_ptr;

__device__ __forceinline__ void async_cp16(const void* g, void* l) {
  // LDS dest is wave-uniform base; HW adds lane*16 (m104/m108).
  __builtin_amdgcn_global_load_lds((gas_ptr)g, (las_ptr)l, 16, 0, 0);
}

__device__ __forceinline__ unsigned short f2bf(float x) {
  union { float f; unsigned int u; } v; v.f = x;
  unsigned int r = v.u + 0x7FFFu + ((v.u >> 16) & 1u);  // RNE
  return (unsigned short)(r >> 16);
}

// ---------------------------------------------------------------------------
// Convert Q,K fp32 -> Z bf16 [4][4096][512] (rows 0..2047 = Q, 2048.. = K)
// ---------------------------------------------------------------------------
__global__ __launch_bounds__(256) void convert_bf16_kernel(
    const float* __restrict__ Q, const float* __restrict__ K,
    unsigned short* __restrict__ Z) {
  int tid = blockIdx.x * 256 + threadIdx.x;  // 0..1048575
  int row = tid >> 6;                        // b*4096 + i
  int c0 = (tid & 63) * 8;
  int b = row >> 12, i = row & 4095;
  const float* src = (i < 2048)
      ? Q + ((size_t)(b * 2048 + i) * 512 + c0)
      : K + ((size_t)(b * 2048 + (i - 2048)) * 512 + c0);
  float4 v0 = ((const float4*)src)[0];
  float4 v1 = ((const float4*)src)[1];
  ushort8 o;
  o[0] = f2bf(v0.x); o[1] = f2bf(v0.y); o[2] = f2bf(v0.z); o[3] = f2bf(v0.w);
  o[4] = f2bf(v1.x); o[5] = f2bf(v1.y); o[6] = f2bf(v1.z); o[7] = f2bf(v1.w);
  *(ushort8*)(Z + (size_t)row * 512 + c0) = o;
}

// ---------------------------------------------------------------------------
// Temporal gram tile (128x128) via 16x16x32 bf16 MFMA + fused LSE partials.
// Grid (cj=32, ri=32, b=4). Per-tile per-row (max, sumexp) -> part[b][row][64].
// LDS layout [row][chunk] with chunk XOR-swizzled by (row>>1)&3 -> 2-way
// bank aliasing only (free). Staged via global_load_lds width=16.
// ---------------------------------------------------------------------------
__global__ __launch_bounds__(256) void temporal_gemm_kernel(
    const unsigned short* __restrict__ Z, float2* __restrict__ part) {
  int cj = blockIdx.x, ri = blockIdx.y, b = blockIdx.z;
  const unsigned short* Zb = Z + (size_t)b * 4096 * 512;

  __shared__ __align__(16) unsigned short As[128 * 32];
  __shared__ __align__(16) unsigned short Bs[128 * 32];

  int tid = threadIdx.x;
  int w = tid >> 6, lane = tid & 63;
  int wr = w >> 1, wc = w & 1;
  int lm = lane & 15, q = lane >> 4;
  int swz = q ^ ((lm >> 1) & 3);  // frag-read chunk swizzle

  // Staging: slot (row_loc = it*64 + w*16 + lane>>2, chunk_st = lane&3)
  // holds real k-chunk kq = chunk_st ^ ((row_loc>>1)&3) = chunk_st ^ ((lane>>3)&3)
  int srow = lane >> 2;
  int kq = (lane & 3) ^ ((lane >> 3) & 3);
  int rl0 = w * 16 + srow;
  int rl1 = 64 + rl0;
  const unsigned short* gA0 = Zb + (size_t)(ri * 128 + rl0) * 512 + kq * 8;
  const unsigned short* gA1 = Zb + (size_t)(ri * 128 + rl1) * 512 + kq * 8;
  const unsigned short* gB0 = Zb + (size_t)(cj * 128 + rl0) * 512 + kq * 8;
  const unsigned short* gB1 = Zb + (size_t)(cj * 128 + rl1) * 512 + kq * 8;
  unsigned short* lA0 = As + (w * 16) * 32;         // wave-uniform bases
  unsigned short* lA1 = As + (64 + w * 16) * 32;
  unsigned short* lB0 = Bs + (w * 16) * 32;
  unsigned short* lB1 = Bs + (64 + w * 16) * 32;

  f32x4 acc[4][4];
#pragma unroll
  for (int mi = 0; mi < 4; mi++)
#pragma unroll
    for (int ni = 0; ni < 4; ni++) acc[mi][ni] = (f32x4)(0.f);

  for (int kc = 0; kc < 16; ++kc) {
    int go = kc * 32;  // ushort offset along k
    async_cp16(gA0 + go, lA0);
    async_cp16(gA1 + go, lA1);
    async_cp16(gB0 + go, lB0);
    async_cp16(gB1 + go, lB1);
    __syncthreads();

    short8 af[4], bfr[4];
#pragma unroll
    for (int mi = 0; mi < 4; mi++) {
      int ar = wr * 64 + mi * 16 + lm;
      af[mi] = *(const short8*)(As + ar * 32 + swz * 8);
    }
#pragma unroll
    for (int ni = 0; ni < 4; ni++) {
      int bc = wc * 64 + ni * 16 + lm;
      bfr[ni] = *(const short8*)(Bs + bc * 32 + swz * 8);
    }
#pragma unroll
    for (int mi = 0; mi < 4; mi++)
#pragma unroll
      for (int ni = 0; ni < 4; ni++)
        acc[mi][ni] = __builtin_amdgcn_mfma_f32_16x16x32_bf16(
            af[mi], bfr[ni], acc[mi][ni], 0, 0, 0);
    __syncthreads();
  }

  // Epilogue: C/D layout col=lane&15, row=(lane>>4)*4+reg (m89-verified).
  // Per-row reduce across the 16 col-lanes (xor 1,2,4,8 keeps q fixed).
#pragma unroll
  for (int mi = 0; mi < 4; mi++) {
#pragma unroll
    for (int r = 0; r < 4; r++) {
      int R = ri * 128 + wr * 64 + mi * 16 + q * 4 + r;
      float vals[4];
      float mt = -INFINITY;
#pragma unroll
      for (int ni = 0; ni < 4; ni++) {
        float v = acc[mi][ni][r];
        int Cg = cj * 128 + wc * 64 + ni * 16 + lm;
        if (R == Cg) v = -INFINITY;  // exclude diagonal j==i
        vals[ni] = v;
        mt = fmaxf(mt, v);
      }
      mt = fmaxf(mt, __shfl_xor(mt, 1));
      mt = fmaxf(mt, __shfl_xor(mt, 2));
      mt = fmaxf(mt, __shfl_xor(mt, 4));
      mt = fmaxf(mt, __shfl_xor(mt, 8));
      float st = 0.f;
#pragma unroll
      for (int ni = 0; ni < 4; ni++) st += __expf(vals[ni] - mt);
      st += __shfl_xor(st, 1);
      st += __shfl_xor(st, 2);
      st += __shfl_xor(st, 4);
      st += __shfl_xor(st, 8);
      if (lm == 0) {
        float2 ms; ms.x = mt; ms.y = st;
        part[((size_t)(b * 4096 + R)) * 64 + cj * 2 + wc] = ms;
      }
    }
  }
}

// Merge 64 per-tile partials per row -> lse_temp[b*4096+row]. 1 wave/row.
__global__ __launch_bounds__(64) void merge_row_kernel(
    const float2* __restrict__ part, float* __restrict__ lse_temp) {
  int row = blockIdx.x;  // 0..16383
  int p = threadIdx.x;
  float2 v = part[(size_t)row * 64 + p];
  float M = v.x;
  M = fmaxf(M, __shfl_xor(M, 1));
  M = fmaxf(M, __shfl_xor(M, 2));
  M = fmaxf(M, __shfl_xor(M, 4));
  M = fmaxf(M, __shfl_xor(M, 8));
  M = fmaxf(M, __shfl_xor(M, 16));
  M = fmaxf(M, __shfl_xor(M, 32));
  float st = v.y * __expf(v.x - M);
  st += __shfl_xor(st, 1);
  st += __shfl_xor(st, 2);
  st += __shfl_xor(st, 4);
  st += __shfl_xor(st, 8);
  st += __shfl_xor(st, 16);
  st += __shfl_xor(st, 32);
  if (p == 0) lse_temp[row] = M + __logf(st);
}

// ---------------------------------------------------------------------------
// Instance LSE (fp32): per t, 8x8 gram of {Q[b,t],K[b,t]}; LSE_j!=i per row.
// Also posdot[b][t] = dot(Q[b,t],K[b,t]) in fp32.
// ---------------------------------------------------------------------------
__global__ __launch_bounds__(256) void instance_kernel(
    const float* __restrict__ Q, const float* __restrict__ K,
    float* __restrict__ lse_inst /* [2048][8] */,
    float* __restrict__ posdot /* [4][2048] */) {
  int t = (blockIdx.x * 256 + threadIdx.x) >> 6;
  if (t >= 2048) return;
  int lane = threadIdx.x & 63;
  int i = lane >> 3, j = lane & 7;
  const float* vi = (i < 4) ? Q + ((size_t)i * 2048 + t) * 512 : K + ((size_t)(i - 4) * 2048 + t) * 512;
  const float* vj = (j < 4) ? Q + ((size_t)j * 2048 + t) * 512 : K + ((size_t)(j - 4) * 2048 + t) * 512;
  float d = 0.f;
  for (int c = 0; c < 512; c += 4) {
    float4 a = *(const float4*)(vi + c);
    float4 bb = *(const float4*)(vj + c);
    d = fmaf(a.x, bb.x, d);
    d = fmaf(a.y, bb.y, d);
    d = fmaf(a.z, bb.z, d);
    d = fmaf(a.w, bb.w, d);
  }
  float dd = (i == j) ? -INFINITY : d;
  float mt = dd;
  mt = fmaxf(mt, __shfl_xor(mt, 1, 64));
  mt = fmaxf(mt, __shfl_xor(mt, 2, 64));
  mt = fmaxf(mt, __shfl_xor(mt, 4, 64));
  float e = __expf(dd - mt);
  e += __shfl_xor(e, 1, 64);
  e += __shfl_xor(e, 2, 64);
  e += __shfl_xor(e, 4, 64);
  if (j == 0) lse_inst[t * 8 + i] = mt + __logf(e);
  if (i < 4 && j == i + 4) posdot[i * 2048 + t] = d;
}

// ---------------------------------------------------------------------------
// Fused combine + top-7. One block of 256 threads; each thread owns 8 t's in
// registers. 7 rounds of (local max -> wave shfl argmax -> 4-wave LDS
// combine), lower-index tiebreak, owner invalidates. Replaces the serial
// tid==0 scan that was 131 us of single-lane LDS latency.
// ---------------------------------------------------------------------------
__global__ __launch_bounds__(256) void combine_topk_kernel(
    const float* __restrict__ lse_inst, const float* __restrict__ lse_temp,
    const float* __restrict__ posdot, int* __restrict__ index_out) {
  __shared__ float wmax[4];
  __shared__ int widx[4];
  int tid = threadIdx.x;
  int base = tid * 8;
  float v[8];
#pragma unroll
  for (int r = 0; r < 8; r++) {
    int t = base + r;
    float sum = 0.f;
#pragma unroll
    for (int b = 0; b < 4; b++) {
      sum += 0.25f * (lse_inst[t * 8 + b] + lse_inst[t * 8 + 4 + b] +
                      lse_temp[b * 4096 + t] + lse_temp[b * 4096 + 2048 + t]) -
             posdot[b * 2048 + t];
    }
    v[r] = sum * 0.25f;
  }
  int lane = tid & 63, w = tid >> 6;
  for (int k = 0; k < 7; k++) {
    float bv = v[0];
    int bi = base;
#pragma unroll
    for (int r = 1; r < 8; r++)
      if (v[r] > bv) { bv = v[r]; bi = base + r; }
#pragma unroll
    for (int d = 1; d < 64; d <<= 1) {
      float ov = __shfl_xor(bv, d);
      int oi = __shfl_xor(bi, d);
      if (ov > bv || (ov == bv && oi < bi)) { bv = ov; bi = oi; }
    }
    if (lane == 0) { wmax[w] = bv; widx[w] = bi; }
    __syncthreads();
    float BV = wmax[0];
    int BI = widx[0];
#pragma unroll
    for (int ww = 1; ww < 4; ww++)
      if (wmax[ww] > BV || (wmax[ww] == BV && widx[ww] < BI)) {
        BV = wmax[ww];
        BI = widx[ww];
      }
    if (tid == 0) index_out[k] = BI;
    if (BI >= base && BI < base + 8) v[BI - base] = -INFINITY;
    __syncthreads();  // protect wmax/widx before next round's overwrite
  }
}

// Cumsum over L per (b,h,e), chunked. Phase 1: per-chunk sums.
__global__ __launch_bounds__(64) void cumsum_phase1(const float* __restrict__ V,
                                                    float* __restrict__ partial) {
  int blk = blockIdx.x;  // (b*8+h)*16 + chunk
  int chunk = blk & 15;
  int bh = blk >> 4;
  int h = bh & 7, b = bh >> 3;
  int e = threadIdx.x;
  float s = 0.f;
  int l0 = chunk * 128;
  for (int l = l0; l < l0 + 128; l++)
    s += V[((size_t)(b * 2048 + l) * 8 + h) * 64 + e];
  partial[blk * 64 + e] = s;
}

// Phase 2: local scan + write; selected positions -> running mean.
__global__ __launch_bounds__(64) void cumsum_phase2(const float* __restrict__ V,
                                                    const float* __restrict__ partial,
                                                    const int* __restrict__ index,
                                                    float* __restrict__ out) {
  int blk = blockIdx.x;
  int chunk = blk & 15;
  int bh = blk >> 4;
  int h = bh & 7, b = bh >> 3;
  int e = threadIdx.x;
  float run = 0.f;
  for (int c = 0; c < chunk; c++) run += partial[(bh * 16 + c) * 64 + e];
  int idx[7];
#pragma unroll
  for (int k = 0; k < 7; k++) idx[k] = index[k];
  int l0 = chunk * 128;
  for (int l = l0; l < l0 + 128; l++) {
    run += V[((size_t)(b * 2048 + l) * 8 + h) * 64 + e];
    float o = run;
    bool special = false;
#pragma unroll
    for (int k = 0; k < 7; k++) special = special || (idx[k] == l);
    if (special) o = run / (float)(l + 1);
    out[((size_t)bh * 2048 + l) * 64 + e] = o;
  }
}

extern "C" void kernel_launch(void* const* d_in, const int* in_sizes, int n_in,
                              void* d_out, int out_size, void* d_ws, size_t ws_size,
                              hipStream_t stream) {
  const float* Q = (const float*)d_in[0];  // (4,2048,512)
  const float* K = (const float*)d_in[1];
  const float* V = (const float*)d_in[2];
  float* out = (float*)d_out;              // (4,8,2048,64)

  // Workspace layout:
  unsigned short* Z = (unsigned short*)d_ws;        // 4*4096*512 bf16 = 16.8 MB
  float* base = (float*)d_ws + 4 * 4096 * 512 / 2;  // after Z
  float2* part2 = (float2*)base;                    // 4*4096*64 float2 = 8.4 MB
  float* lse_t = base + 2 * 4 * 4096 * 64;          // 16384
  float* lse_i = lse_t + 16384;                     // 16384
  float* posd = lse_i + 16384;                      // 8192
  int* idx = (int*)(posd + 8192);                   // 8
  float* cpart = posd + 8192 + 8;                   // 32768

  convert_bf16_kernel<<<4096, 256, 0, stream>>>(Q, K, Z);
  temporal_gemm_kernel<<<dim3(32, 32, 4), 256, 0, stream>>>(Z, part2);
  instance_kernel<<<512, 256, 0, stream>>>(Q, K, lse_i, posd);
  merge_row_kernel<<<16384, 64, 0, stream>>>(part2, lse_t);
  combine_topk_kernel<<<1, 256, 0, stream>>>(lse_i, lse_t, posd, idx);
  cumsum_phase1<<<512, 64, 0, stream>>>(V, cpart);
  cumsum_phase2<<<512, 64, 0, stream>>>(V, cpart, idx, out);
}